// Round 4
// baseline (273.309 us; speedup 1.0000x reference)
//
#include <hip/hip_runtime.h>
#include <math.h>

#define HH 384
#define WW 384
#define W4 96            // WW / 4 segments
#define YO8 48           // HH / 8 row-octaves
#define NIMG 272         // 16 * 17
#define IMG_STRIDE (HH * WW)
#define TOTAL_THR (NIMG * YO8 * W4)   // 1,253,376 = 4896 * 256 exactly

typedef float f4_t __attribute__((ext_vector_type(4)));

__device__ __forceinline__ float fast_sigmoid(float v) {
    // identical formula to the passing R3 kernel (absmax 0.0039)
    return __fdividef(1.0f, 1.0f + __expf(-v));
}

__device__ __forceinline__ float max3f(float a, float b, float c) {
    return fmaxf(fmaxf(a, b), c);   // -> v_max3_f32
}

__global__ __launch_bounds__(256) void
heatmap_peaks_kernel(const float* __restrict__ in, float* __restrict__ out) {
    int vi   = blockIdx.x * 256 + threadIdx.x;
    int lane = threadIdx.x & 63;

    int x4   = vi % W4;
    int rest = vi / W4;
    int yo   = rest % YO8;
    int bk   = rest / YO8;
    int y0   = yo * 8;

    const float NEG = -INFINITY;
    const float* base = in + (size_t)bk * IMG_STRIDE + x4 * 4;

    // Load 10 rows (y0-1 .. y0+8), clamped; out-of-range rows become -inf.
    float4 R[10];
#pragma unroll
    for (int j = 0; j < 10; ++j) {
        int yy = y0 - 1 + j;
        bool valid = (yy >= 0) && (yy < HH);
        int yc = yy < 0 ? 0 : (yy >= HH ? HH - 1 : yy);
        float4 v = *(const float4*)(base + (size_t)yc * WW);
        if (!valid) v = make_float4(NEG, NEG, NEG, NEG);
        R[j] = v;
    }

    // Lane-edge halo columns (only lane 0 / lane 63 of a wave need global
    // loads for x0-1 / x0+4; everyone else gets them via shuffle of vm).
    float cl[10], cr[10];
#pragma unroll
    for (int j = 0; j < 10; ++j) { cl[j] = NEG; cr[j] = NEG; }

    bool has_l = (x4 > 0) && (lane == 0);
    bool has_r = (x4 < W4 - 1) && (lane == 63);
    if (has_l) {
#pragma unroll
        for (int j = 0; j < 10; ++j) {
            int yy = y0 - 1 + j;
            if (yy >= 0 && yy < HH) cl[j] = base[(size_t)yy * WW - 1];
        }
    }
    if (has_r) {
#pragma unroll
        for (int j = 0; j < 10; ++j) {
            int yy = y0 - 1 + j;
            if (yy >= 0 && yy < HH) cr[j] = base[(size_t)yy * WW + 4];
        }
    }

    float* ob = out + (size_t)bk * IMG_STRIDE + (size_t)y0 * WW + x4 * 4;

#pragma unroll
    for (int r = 0; r < 8; ++r) {
        float4 A = R[r], B = R[r + 1], C = R[r + 2];
        // vertical 3-max per column
        float4 vm;
        vm.x = max3f(A.x, B.x, C.x);
        vm.y = max3f(A.y, B.y, C.y);
        vm.z = max3f(A.z, B.z, C.z);
        vm.w = max3f(A.w, B.w, C.w);

        // horizontal halos of the column-max via cross-lane shuffle
        float lvm = __shfl_up(vm.w, 1);
        float rvm = __shfl_down(vm.x, 1);
        if (x4 == 0)            lvm = NEG;
        else if (lane == 0)     lvm = max3f(cl[r], cl[r + 1], cl[r + 2]);
        if (x4 == W4 - 1)       rvm = NEG;
        else if (lane == 63)    rvm = max3f(cr[r], cr[r + 1], cr[r + 2]);

        float4 m;
        m.x = max3f(lvm,  vm.x, vm.y);
        m.y = max3f(vm.x, vm.y, vm.z);
        m.z = max3f(vm.y, vm.z, vm.w);
        m.w = max3f(vm.z, vm.w, rvm);

        float p;
        f4_t o;
        p = fast_sigmoid(B.x); o.x = (m.x == B.x && p > 0.05f) ? p : 0.0f;
        p = fast_sigmoid(B.y); o.y = (m.y == B.y && p > 0.05f) ? p : 0.0f;
        p = fast_sigmoid(B.z); o.z = (m.z == B.z && p > 0.05f) ? p : 0.0f;
        p = fast_sigmoid(B.w); o.w = (m.w == B.w && p > 0.05f) ? p : 0.0f;

        // output is never re-read: bypass cache allocation
        __builtin_nontemporal_store(o, (f4_t*)(ob + (size_t)r * WW));
    }
}

extern "C" void kernel_launch(void* const* d_in, const int* in_sizes, int n_in,
                              void* d_out, int out_size, void* d_ws, size_t ws_size,
                              hipStream_t stream) {
    const float* in = (const float*)d_in[0];
    float* out = (float*)d_out;
    int blocks = TOTAL_THR / 256;  // 4896
    heatmap_peaks_kernel<<<blocks, 256, 0, stream>>>(in, out);
}

// Round 5
// 260.786 us; speedup vs baseline: 1.0480x; 1.0480x over previous
//
#include <hip/hip_runtime.h>
#include <math.h>

#define HH 384
#define WW 384
#define TW 64
#define TH 64
#define TX 6            // tiles per image row
#define TY 6
#define NIMG 272        // 16 * 17
#define IMG_STRIDE (HH * WW)
#define LDS_W 67        // 66 data + 1 pad (odd stride breaks bank patterns)
#define NELEM (66 * 66) // 4356
#define NLOAD 18        // ceil(4356 / 256)

typedef float f4_t __attribute__((ext_vector_type(4)));

__device__ __forceinline__ float max3f(float a, float b, float c) {
    return fmaxf(fmaxf(a, b), c);   // -> v_max3_f32
}
__device__ __forceinline__ float fast_sigmoid(float v) {
    return __fdividef(1.0f, 1.0f + __expf(-v));
}

__global__ __launch_bounds__(256) void
heatmap_peaks_kernel(const float* __restrict__ in, float* __restrict__ out) {
    __shared__ float S[66 * LDS_W];

    int tid = threadIdx.x;
    int bid = blockIdx.x;
    int txt = bid % TX;
    int tmp = bid / TX;
    int tyt = tmp % TY;
    int img = tmp / TY;
    int x0 = txt * TW;
    int y0 = tyt * TH;

    const float* ib = in + (size_t)img * IMG_STRIDE;
    const float NEG = -INFINITY;

    // ---- stage 66x66 halo tile: all loads independent, issued before any
    // wait; one vmcnt drain instead of a serialized load-wait chain ----
    float va[NLOAD];
    bool  ok[NLOAD];
    int   le[NLOAD];
#pragma unroll
    for (int k = 0; k < NLOAD; ++k) {
        int e  = tid + k * 256;
        int ly = e / 66;
        int lx = e - ly * 66;
        int gx = x0 - 1 + lx;
        int gy = y0 - 1 + ly;
        bool valid = (e < NELEM) && ((unsigned)gx < (unsigned)WW)
                                 && ((unsigned)gy < (unsigned)HH);
        int cx = valid ? gx : 0;
        int cy = valid ? gy : 0;
        va[k] = ib[cy * WW + cx];     // clamped address, independent load
        ok[k] = valid;
        le[k] = ly * LDS_W + lx;
    }
#pragma unroll
    for (int k = 0; k < NLOAD; ++k) {
        int e = tid + k * 256;
        if (e < NELEM) S[le[k]] = ok[k] ? va[k] : NEG;
    }
    __syncthreads();

    // ---- compute: thread -> 4x4 output block ----
    int ctx = tid & 15;         // 16 x-groups of 4 px
    int cty = tid >> 4;         // 16 y-groups of 4 rows
    int rb  = cty * 4;          // lds row of (output row - 1)
    int cb  = ctx * 4;          // lds col of (output col - 1)

    float vals[6][6];
#pragma unroll
    for (int c = 0; c < 6; ++c)
#pragma unroll
        for (int r = 0; r < 6; ++r)
            vals[c][r] = S[(rb + r) * LDS_W + cb + c];

    // vertical 3-max per column
    float vm[6][4];
#pragma unroll
    for (int c = 0; c < 6; ++c)
#pragma unroll
        for (int r = 0; r < 4; ++r)
            vm[c][r] = max3f(vals[c][r], vals[c][r + 1], vals[c][r + 2]);

    float* ob = out + (size_t)img * IMG_STRIDE
                    + (size_t)(y0 + rb) * WW + x0 + cb;
#pragma unroll
    for (int r = 0; r < 4; ++r) {
        f4_t o;
        float p, m, v;
        m = max3f(vm[0][r], vm[1][r], vm[2][r]); v = vals[1][r + 1];
        p = fast_sigmoid(v); o.x = (m == v && p > 0.05f) ? p : 0.0f;
        m = max3f(vm[1][r], vm[2][r], vm[3][r]); v = vals[2][r + 1];
        p = fast_sigmoid(v); o.y = (m == v && p > 0.05f) ? p : 0.0f;
        m = max3f(vm[2][r], vm[3][r], vm[4][r]); v = vals[3][r + 1];
        p = fast_sigmoid(v); o.z = (m == v && p > 0.05f) ? p : 0.0f;
        m = max3f(vm[3][r], vm[4][r], vm[5][r]); v = vals[4][r + 1];
        p = fast_sigmoid(v); o.w = (m == v && p > 0.05f) ? p : 0.0f;
        // output never re-read: keep L2/L3 for the input stream
        __builtin_nontemporal_store(o, (f4_t*)(ob + (size_t)r * WW));
    }
}

extern "C" void kernel_launch(void* const* d_in, const int* in_sizes, int n_in,
                              void* d_out, int out_size, void* d_ws, size_t ws_size,
                              hipStream_t stream) {
    const float* in = (const float*)d_in[0];
    float* out = (float*)d_out;
    int blocks = TX * TY * NIMG;   // 9792
    heatmap_peaks_kernel<<<blocks, 256, 0, stream>>>(in, out);
}